// Round 17
// baseline (674.642 us; speedup 1.0000x reference)
//
#include <hip/hip_runtime.h>

typedef __attribute__((ext_vector_type(8))) short short8;
typedef __attribute__((ext_vector_type(4))) short short4v;
typedef __attribute__((ext_vector_type(8))) unsigned short ushort8v;
typedef __attribute__((ext_vector_type(4))) float f32x4;
typedef __attribute__((ext_vector_type(4))) int int4v;
typedef __attribute__((ext_vector_type(4))) unsigned short ushort4v;
typedef __attribute__((ext_vector_type(2))) unsigned short ushort2v;

#define SCALE_F 0.0625f   // C^-0.5 = 256^-0.5
#define EPS_F 1e-5f

__device__ __forceinline__ float bf2f(unsigned short u) {
  unsigned int i = ((unsigned int)u) << 16;
  return __builtin_bit_cast(float, i);
}
__device__ __forceinline__ unsigned short f2bf(float f) {
  unsigned int i = __builtin_bit_cast(unsigned int, f);
  i += 0x7fffu + ((i >> 16) & 1u);
  return (unsigned short)(i >> 16);
}

// tanh-form GELU ~10 VALU ops; |err| < 5e-4 for |v|<2 (our sigma ~0.32).
__device__ __forceinline__ float fast_gelu(float v) {
  float s = v * v;
  float u = v * __builtin_fmaf(s, 0.0713548163f, 1.5957691216f);
  float e = __expf(u);
  float r = __builtin_amdgcn_rcpf(e + 1.f);
  return v - v * r;
}

__device__ __forceinline__ void gload_lds16(const unsigned short* g, unsigned short* l) {
  __builtin_amdgcn_global_load_lds(
      (const __attribute__((address_space(1))) void*)g,
      (__attribute__((address_space(3))) void*)l, 16, 0, 0);
}

// ---- cast weight [K,N] f32 -> [N,K] bf16 (transposed) ----
template<int K, int N>
__global__ void cast_wt(const float* __restrict__ src, unsigned short* __restrict__ dst) {
  int id = blockIdx.x * 256 + threadIdx.x;          // id = n*K + k
  if (id >= K * N) return;
  int k = id % K, n = id / K;
  dst[id] = f2bf(src[(size_t)k * N + n]);
}

// ---- precompute relative-position bias [head][i][j] ----
__global__ void build_relb(const float* __restrict__ table, float* __restrict__ relb) {
  int id = blockIdx.x * 256 + threadIdx.x;          // 8*64*64
  int h = id >> 12, i = (id >> 6) & 63, j = id & 63;
  int dy = (i >> 3) - (j >> 3) + 7;
  int dx = (i & 7) - (j & 7) + 7;
  relb[id] = table[(dy * 15 + dx) * 8 + h];
}

// ---- window partition + LN1 (coalesced transpose): x[B,C,64,64] ->
//      h bf16 [M,256] (normalized) AND xw bf16 [M,256] (raw, for merge residual)
#define PLN_RS 264   // LDS row stride in ushorts (256 + 8 pad)
__global__ __launch_bounds__(256) void part_ln1(
    const float* __restrict__ x, const float* __restrict__ g, const float* __restrict__ bb,
    unsigned short* __restrict__ h, unsigned short* __restrict__ xw) {
  __shared__ __align__(16) unsigned short t_lds[128 * PLN_RS];
  __shared__ float ps_sum[128][2];
  __shared__ float ps_ss[128][2];
  const int tid = threadIdx.x;
  const int bid = blockIdx.x;
  const int b = bid >> 5, wr = (bid >> 2) & 7, cp = bid & 3;
  const int r0 = wr * 8;            // image row base
  const int c0 = cp * 16;           // image col base

  // Phase 1: coalesced read + transpose to LDS [px][ch]
  const int q = tid & 3, r = (tid >> 2) & 7, cb = tid >> 5;   // cb in 0..7
  const float* xb = x + (size_t)b * 256 * 4096 + (size_t)(r0 + r) * 64 + c0 + q * 4;
#pragma unroll
  for (int it = 0; it < 16; it++) {
    int cpair = it * 8 + cb;                 // channel pair 0..127
    const float* p0 = xb + (size_t)(2 * cpair) * 4096;
    f32x4 v0 = *(const f32x4*)p0;
    f32x4 v1 = *(const f32x4*)(p0 + 4096);
#pragma unroll
    for (int j = 0; j < 4; j++) {
      int px = r * 16 + q * 4 + j;
      ushort2v u = { f2bf(v0[j]), f2bf(v1[j]) };
      *(ushort2v*)(&t_lds[px * PLN_RS + 2 * cpair]) = u;
    }
  }
  __syncthreads();

  // Phase 2: per-pixel stats (2 threads per pixel)
  {
    const int p = tid & 127, half = tid >> 7;
    float sum = 0.f, ss = 0.f;
#pragma unroll
    for (int i = 0; i < 16; i++) {
      ushort8v u = *(const ushort8v*)(&t_lds[p * PLN_RS + half * 128 + i * 8]);
#pragma unroll
      for (int e = 0; e < 8; e++) { float f = bf2f(u[e]); sum += f; ss += f * f; }
    }
    ps_sum[p][half] = sum;
    ps_ss[p][half] = ss;
  }
  __syncthreads();

  // Phase 3: normalize + coalesced write (h normalized, xw raw)
#pragma unroll
  for (int w = 0; w < 16; w++) {
    int id = w * 256 + tid;
    int p = id >> 5, ch = id & 31;
    float mu = (ps_sum[p][0] + ps_sum[p][1]) * (1.f / 256.f);
    float var = (ps_ss[p][0] + ps_ss[p][1]) * (1.f / 256.f) - mu * mu;
    float rs = rsqrtf(var + EPS_F);
    ushort8v u = *(const ushort8v*)(&t_lds[p * PLN_RS + ch * 8]);
    f32x4 g0 = *(const f32x4*)(g + ch * 8);
    f32x4 g1 = *(const f32x4*)(g + ch * 8 + 4);
    f32x4 b0 = *(const f32x4*)(bb + ch * 8);
    f32x4 b1 = *(const f32x4*)(bb + ch * 8 + 4);
    ushort8v o;
#pragma unroll
    for (int e = 0; e < 4; e++) {
      o[e]     = f2bf((bf2f(u[e])     - mu) * rs * g0[e] + b0[e]);
      o[e + 4] = f2bf((bf2f(u[e + 4]) - mu) * rs * g1[e] + b1[e]);
    }
    int rr = p >> 4, col = p & 15;
    size_t m = (size_t)b * 4096 + (size_t)(wr * 8 + cp * 2 + (col >> 3)) * 64 + rr * 8 + (col & 7);
    *(ushort8v*)(h + m * 256 + ch * 8) = o;
    *(ushort8v*)(xw + m * 256 + ch * 8) = u;   // raw x, window-partitioned
  }
}

// ---- GEMM: A bf16 [rows,K] x Bt bf16 [N,K] -> out, 128x128 tile, 4 waves ----
enum { EPI_QKV = 0, EPI_MERGE = 1 };

template<int EPI>
__device__ __forceinline__ void gemm_body(
    unsigned short* As, unsigned short* Bs,
    const unsigned short* __restrict__ A, const unsigned short* __restrict__ Bt,
    const float* __restrict__ bias, const void* __restrict__ res,
    void* __restrict__ out, int K, int N, long m_base) {
  const int tid = threadIdx.x;
  const int l15 = tid & 15, lhi = (tid & 63) >> 4;
  const int wid = tid >> 6, wm = wid >> 1, wn = wid & 1;
  const size_t m0 = (size_t)blockIdx.x * 128;
  const int n0 = blockIdx.y * 128;
  const int row_s = tid >> 3, kc8 = (tid & 7) * 8;   // staging coords

  auto stage = [&](int kb, int k0) {
#pragma unroll
    for (int i = 0; i < 4; i++) {
      int row = i * 32 + row_s;
      gload_lds16(A + (m0 + row) * (size_t)K + k0 + kc8, &As[kb * 8192 + (i * 256 + tid) * 8]);
      gload_lds16(Bt + (size_t)(n0 + row) * (size_t)K + k0 + kc8, &Bs[kb * 8192 + (i * 256 + tid) * 8]);
    }
  };

  f32x4 acc[4][4];
#pragma unroll
  for (int i = 0; i < 4; i++)
#pragma unroll
    for (int j = 0; j < 4; j++) acc[i][j] = (f32x4){0.f, 0.f, 0.f, 0.f};

  stage(0, 0);
  int kb = 0;
  for (int k0 = 0; k0 < K; k0 += 64, kb ^= 1) {
    if (k0 + 64 < K) {
      stage(kb ^ 1, k0 + 64);
      asm volatile("s_waitcnt vmcnt(8)" ::: "memory");
    } else {
      asm volatile("s_waitcnt vmcnt(0)" ::: "memory");
    }
    __builtin_amdgcn_s_barrier();
#pragma unroll
    for (int ks = 0; ks < 2; ks++) {
      short8 af[4], bfr[4];
#pragma unroll
      for (int t = 0; t < 4; t++) {
        af[t]  = *(const short8*)(&As[kb * 8192 + (wm * 64 + t * 16 + l15) * 64 + ks * 32 + lhi * 8]);
        bfr[t] = *(const short8*)(&Bs[kb * 8192 + (wn * 64 + t * 16 + l15) * 64 + ks * 32 + lhi * 8]);
      }
#pragma unroll
      for (int mt = 0; mt < 4; mt++)
#pragma unroll
        for (int nt = 0; nt < 4; nt++)
          acc[mt][nt] = __builtin_amdgcn_mfma_f32_16x16x32_bf16(af[mt], bfr[nt], acc[mt][nt], 0, 0, 0);
    }
    __builtin_amdgcn_s_barrier();
  }

#pragma unroll
  for (int mt = 0; mt < 4; mt++) {
#pragma unroll
    for (int nt = 0; nt < 4; nt++) {
      const size_t gml0 = m0 + wm * 64 + mt * 16 + lhi * 4;
      const size_t gm0 = gml0 + (size_t)m_base;
      const int gn = n0 + wn * 64 + nt * 16 + l15;
      if (EPI == EPI_QKV) {
#pragma unroll
        for (int r = 0; r < 4; r++)
          ((unsigned short*)out)[(gml0 + r) * (size_t)N + gn] = f2bf(acc[mt][nt][r] + bias[gn]);
      } else {  // EPI_MERGE: residual from pre-partitioned bf16 xw (linear, coalesced)
#pragma unroll
        for (int r = 0; r < 4; r++) {
          float v = acc[mt][nt][r] + bias[gn] +
                    bf2f(((const unsigned short*)res)[(gm0 + r) * 256 + gn]);
          ((unsigned short*)out)[(gm0 + r) * 256 + gn] = f2bf(v);
        }
      }
    }
  }
}

#define GEMM_WRAP(name, epi)                                                          \
__global__ __launch_bounds__(256) void name(                                          \
    const unsigned short* __restrict__ A, const unsigned short* __restrict__ Bt,      \
    const float* __restrict__ bias, const void* __restrict__ res,                     \
    void* __restrict__ out, int K, int N, long m_base) {                              \
  __shared__ __align__(16) unsigned short As[2 * 128 * 64];                           \
  __shared__ __align__(16) unsigned short Bs[2 * 128 * 64];                           \
  gemm_body<epi>(As, Bs, A, Bt, bias, res, out, K, N, m_base);                        \
}
GEMM_WRAP(gemm_qkv, EPI_QKV)
GEMM_WRAP(gemm_merge, EPI_MERGE)

// ---- fused LN2+MLP: R8 body + LN2 prologue + reg-pipelined weight loads with
// cross-barrier issue-early (T14): gemm2's first w2 frags issued before the
// pre-gemm2 barrier; next slice's first w1 frags issued inside gemm2.
#define A2S 136   // 272B rows: 16B-aligned b128 reads
__global__ __launch_bounds__(256, 3) void mlp_fused(
    const unsigned short* __restrict__ x2, const unsigned short* __restrict__ w1t,
    const float* __restrict__ b1, const unsigned short* __restrict__ w2t,
    const float* __restrict__ b2, const float* __restrict__ ln2g,
    const float* __restrict__ ln2b, float* __restrict__ out) {
  __shared__ __align__(16) unsigned short Ash[64 * 256];
  __shared__ __align__(16) unsigned short A2sh[64 * A2S];
  const int tid = threadIdx.x;
  const int wid = tid >> 6, l = tid & 63, l15 = l & 15, lhi = l >> 4;
  const size_t m0 = (size_t)blockIdx.x * 64;

  // stage x2 rows into Ash LINEAR
#pragma unroll
  for (int i = 0; i < 8; i++) {
    int uidx = i * 256 + tid;                  // 16B unit 0..2047
    gload_lds16(x2 + m0 * 256 + uidx * 8, &Ash[uidx * 8]);
  }
  asm volatile("s_waitcnt vmcnt(0)" ::: "memory");
  __builtin_amdgcn_s_barrier();

  // LN2 in-place: ALL reads into regs BEFORE any write (wave-lockstep safe).
  {
    const int rl = l & 15;
    const int row = wid * 16 + rl;
    const int p = lhi;
    unsigned short* rp = &Ash[row * 256];
    short8 v[8];
#pragma unroll
    for (int e = 0; e < 8; e++) {
      int u = p * 8 + ((e + rl) & 7);          // rotated: unit%8 varies across rows
      v[e] = *(const short8*)(rp + u * 8);
    }
    float sum = 0.f, ss = 0.f;
#pragma unroll
    for (int e = 0; e < 8; e++)
#pragma unroll
      for (int j = 0; j < 8; j++) {
        float f = bf2f((unsigned short)v[e][j]);
        sum += f; ss += f * f;
      }
    sum += __shfl_xor(sum, 16, 64); ss += __shfl_xor(ss, 16, 64);
    sum += __shfl_xor(sum, 32, 64); ss += __shfl_xor(ss, 32, 64);
    float mu = sum * (1.f / 256.f);
    float var = ss * (1.f / 256.f) - mu * mu;
    float rs = rsqrtf(var + EPS_F);
    const int key = rl << 1;
#pragma unroll
    for (int e = 0; e < 8; e++) {
      int u = p * 8 + ((e + rl) & 7);
      f32x4 g0 = *(const f32x4*)(ln2g + u * 8);
      f32x4 g1 = *(const f32x4*)(ln2g + u * 8 + 4);
      f32x4 b0 = *(const f32x4*)(ln2b + u * 8);
      f32x4 b1v = *(const f32x4*)(ln2b + u * 8 + 4);
      ushort8v o;
#pragma unroll
      for (int j = 0; j < 4; j++) {
        o[j]     = f2bf((bf2f((unsigned short)v[e][j])     - mu) * rs * g0[j] + b0[j]);
        o[j + 4] = f2bf((bf2f((unsigned short)v[e][j + 4]) - mu) * rs * g1[j] + b1v[j]);
      }
      *(ushort8v*)(rp + (u ^ key) * 8) = o;
    }
  }
  __builtin_amdgcn_s_barrier();

  f32x4 oacc[4][4];
#pragma unroll
  for (int i = 0; i < 4; i++)
#pragma unroll
    for (int j = 0; j < 4; j++) oacc[i][j] = (f32x4){0.f, 0.f, 0.f, 0.f};

  // loop-carried first w1 fragments for the upcoming slice's kst=0
  short8 bf1f[2];
#pragma unroll
  for (int nt = 0; nt < 2; nt++)
    bf1f[nt] = *(const short8*)(w1t + (size_t)(wid * 32 + nt * 16 + l15) * 256 + lhi * 8);

  for (int hs = 0; hs < 8; hs++) {
    const int hc0 = hs * 128 + wid * 32;
    // bias loads hoisted (independent of gemm1)
    float bv0 = b1[hc0 + l15], bv1 = b1[hc0 + 16 + l15];

    f32x4 hacc[4][2];
#pragma unroll
    for (int i = 0; i < 4; i++) { hacc[i][0] = (f32x4){0.f,0.f,0.f,0.f}; hacc[i][1] = (f32x4){0.f,0.f,0.f,0.f}; }

    // GEMM1 with ping-pong prefetch; kst=0 frags were prefetched last slice
    short8 bf1p[2][2];
    bf1p[0][0] = bf1f[0]; bf1p[0][1] = bf1f[1];
#pragma unroll
    for (int kst = 0; kst < 8; kst++) {
      if (kst < 7) {
#pragma unroll
        for (int nt = 0; nt < 2; nt++)
          bf1p[(kst + 1) & 1][nt] =
              *(const short8*)(w1t + (size_t)(hc0 + nt * 16 + l15) * 256 + (kst + 1) * 32 + lhi * 8);
      }
      short8 af[4];
#pragma unroll
      for (int mt = 0; mt < 4; mt++) {
        int su = (kst * 4 + lhi) ^ (l15 << 1);
        af[mt] = *(const short8*)(&Ash[(mt * 16 + l15) * 256 + su * 8]);
      }
#pragma unroll
      for (int mt = 0; mt < 4; mt++)
#pragma unroll
        for (int nt = 0; nt < 2; nt++)
          hacc[mt][nt] = __builtin_amdgcn_mfma_f32_16x16x32_bf16(af[mt], bf1p[kst & 1][nt], hacc[mt][nt], 0, 0, 0);
    }

    // issue-early: gemm2's first w2 fragments fly across the barrier
    const unsigned short* w2base = w2t + (size_t)(wid * 64 + l15) * 1024 + hs * 128 + lhi * 8;
    short8 bf2p[2][4];
#pragma unroll
    for (int nt = 0; nt < 4; nt++)
      bf2p[0][nt] = *(const short8*)(w2base + (size_t)(nt * 16) * 1024);

    // bias + GELU -> A2sh
#pragma unroll
    for (int mt = 0; mt < 4; mt++)
#pragma unroll
      for (int nt = 0; nt < 2; nt++) {
        float bv = nt ? bv1 : bv0;
        int kh = wid * 32 + nt * 16 + l15;
#pragma unroll
        for (int rr = 0; rr < 4; rr++) {
          float v = hacc[mt][nt][rr] + bv;
          A2sh[(mt * 16 + lhi * 4 + rr) * A2S + kh] = f2bf(fast_gelu(v));
        }
      }
    __builtin_amdgcn_s_barrier();

    // GEMM2 with ping-pong prefetch; also prefetch next slice's first w1 frags
#pragma unroll
    for (int k2 = 0; k2 < 4; k2++) {
      if (k2 < 3) {
#pragma unroll
        for (int nt = 0; nt < 4; nt++)
          bf2p[(k2 + 1) & 1][nt] = *(const short8*)(w2base + (size_t)(nt * 16) * 1024 + (k2 + 1) * 32);
      }
      if (k2 == 0 && hs < 7) {
#pragma unroll
        for (int nt = 0; nt < 2; nt++)
          bf1f[nt] = *(const short8*)(w1t + (size_t)((hs + 1) * 128 + wid * 32 + nt * 16 + l15) * 256 + lhi * 8);
      }
      short8 a2[4];
#pragma unroll
      for (int mt = 0; mt < 4; mt++)
        a2[mt] = *(const short8*)(&A2sh[(mt * 16 + l15) * A2S + k2 * 32 + lhi * 8]);
      __builtin_amdgcn_s_setprio(1);
#pragma unroll
      for (int mt = 0; mt < 4; mt++)
#pragma unroll
        for (int nt = 0; nt < 4; nt++)
          oacc[mt][nt] = __builtin_amdgcn_mfma_f32_16x16x32_bf16(a2[mt], bf2p[k2 & 1][nt], oacc[mt][nt], 0, 0, 0);
      __builtin_amdgcn_s_setprio(0);
    }
    __builtin_amdgcn_s_barrier();   // A2sh reuse next slice
  }

  // epilogue: + b2 + x2 residual, departition scatter (f32x4)
#pragma unroll
  for (int mt = 0; mt < 4; mt++) {
#pragma unroll
    for (int nt = 0; nt < 4; nt++) {
      size_t gm0 = m0 + mt * 16 + lhi * 4;
      int gn = wid * 64 + nt * 16 + l15;
      int bi = (int)(gm0 >> 12), gg = (int)((gm0 >> 6) & 63), s0 = (int)(gm0 & 63);
      size_t sp = (size_t)((gg >> 3) * 8 + (s0 >> 3)) * 64 + (gg & 7) * 8 + (s0 & 7);
      f32x4 o4;
#pragma unroll
      for (int r = 0; r < 4; r++)
        o4[r] = oacc[mt][nt][r] + b2[gn] + bf2f(x2[(gm0 + r) * 256 + gn]);
      *(f32x4*)(&out[((size_t)(bi * 256 + gn)) * 4096 + sp]) = o4;
    }
  }
}

// ---- attention: one wave per (window, head) ----
__global__ __launch_bounds__(64) void attn_k(
    const unsigned short* __restrict__ qkv, const float* __restrict__ relb,
    unsigned short* __restrict__ o) {
  __shared__ __align__(16) unsigned short p_lds[64 * 72];
  __shared__ __align__(16) unsigned short vt_lds[32 * 72];
  const int l = threadIdx.x;
  const int l15 = l & 15, lhi = l >> 4;
  const int w = blockIdx.x, head = blockIdx.y;
  const unsigned short* base = qkv + (size_t)w * 64 * 768 + head * 32;

  short8 aq[4], bk[4];
#pragma unroll
  for (int t = 0; t < 4; t++) {
    aq[t] = *(const short8*)(base + (t * 16 + l15) * 768 + lhi * 8);
    bk[t] = *(const short8*)(base + 256 + (t * 16 + l15) * 768 + lhi * 8);
  }
  f32x4 s[4][4];
#pragma unroll
  for (int i = 0; i < 4; i++)
#pragma unroll
    for (int j = 0; j < 4; j++) s[i][j] = (f32x4){0.f, 0.f, 0.f, 0.f};
#pragma unroll
  for (int mt = 0; mt < 4; mt++)
#pragma unroll
    for (int nt = 0; nt < 4; nt++)
      s[mt][nt] = __builtin_amdgcn_mfma_f32_16x16x32_bf16(aq[mt], bk[nt], s[mt][nt], 0, 0, 0);

  const float* rb = relb + head * 4096;
  float rsum[4][4];
#pragma unroll
  for (int mt = 0; mt < 4; mt++) {
#pragma unroll
    for (int r = 0; r < 4; r++) {
      int row = mt * 16 + lhi * 4 + r;
      float vv[4];
      float vmax = -1e30f;
#pragma unroll
      for (int nt = 0; nt < 4; nt++) {
        int col = nt * 16 + l15;
        float v = s[mt][nt][r] * SCALE_F + rb[row * 64 + col];
        vv[nt] = v;
        vmax = fmaxf(vmax, v);
      }
#pragma unroll
      for (int d = 1; d < 16; d <<= 1) vmax = fmaxf(vmax, __shfl_xor(vmax, d, 64));
      float sum = 0.f;
#pragma unroll
      for (int nt = 0; nt < 4; nt++) {
        float p = __expf(vv[nt] - vmax);
        sum += p;
        p_lds[row * 72 + nt * 16 + l15] = f2bf(p);
      }
#pragma unroll
      for (int d = 1; d < 16; d <<= 1) sum += __shfl_xor(sum, d, 64);
      rsum[mt][r] = 1.f / sum;
    }
  }

  // stage v^T: vt[dh][token]
#pragma unroll
  for (int j = 0; j < 4; j++) {
    short8 vv = *(const short8*)(base + 512 + l * 768 + j * 8);
#pragma unroll
    for (int e = 0; e < 8; e++)
      vt_lds[(j * 8 + e) * 72 + l] = (unsigned short)vv[e];
  }
  __syncthreads();

  f32x4 o2[4][2];
#pragma unroll
  for (int i = 0; i < 4; i++) { o2[i][0] = (f32x4){0.f,0.f,0.f,0.f}; o2[i][1] = (f32x4){0.f,0.f,0.f,0.f}; }
#pragma unroll
  for (int ks = 0; ks < 2; ks++) {
    short8 ap[4], bv[2];
#pragma unroll
    for (int t = 0; t < 4; t++)
      ap[t] = *(const short8*)(&p_lds[(t * 16 + l15) * 72 + ks * 32 + lhi * 8]);
#pragma unroll
    for (int t = 0; t < 2; t++)
      bv[t] = *(const short8*)(&vt_lds[(t * 16 + l15) * 72 + ks * 32 + lhi * 8]);
#pragma unroll
    for (int mt = 0; mt < 4; mt++)
#pragma unroll
      for (int n2 = 0; n2 < 2; n2++)
        o2[mt][n2] = __builtin_amdgcn_mfma_f32_16x16x32_bf16(ap[mt], bv[n2], o2[mt][n2], 0, 0, 0);
  }
#pragma unroll
  for (int mt = 0; mt < 4; mt++)
#pragma unroll
    for (int n2 = 0; n2 < 2; n2++)
#pragma unroll
      for (int r = 0; r < 4; r++) {
        int row = mt * 16 + lhi * 4 + r;
        int dh = n2 * 16 + l15;
        o[((size_t)w * 64 + row) * 256 + head * 32 + dh] = f2bf(o2[mt][n2][r] * rsum[mt][r]);
      }
}

extern "C" void kernel_launch(void* const* d_in, const int* in_sizes, int n_in,
                              void* d_out, int out_size, void* d_ws, size_t ws_size,
                              hipStream_t stream) {
  (void)in_sizes; (void)n_in; (void)out_size;
  const float* x          = (const float*)d_in[0];
  const float* ln1_g      = (const float*)d_in[1];
  const float* ln1_b      = (const float*)d_in[2];
  const float* qkv_w      = (const float*)d_in[3];
  const float* qkv_b      = (const float*)d_in[4];
  const float* merge_w    = (const float*)d_in[5];
  const float* merge_b    = (const float*)d_in[6];
  const float* bias_table = (const float*)d_in[7];
  const float* ln2_g      = (const float*)d_in[8];
  const float* ln2_b      = (const float*)d_in[9];
  const float* mlp_w1     = (const float*)d_in[10];
  const float* mlp_b1     = (const float*)d_in[11];
  const float* mlp_w2     = (const float*)d_in[12];
  const float* mlp_b2     = (const float*)d_in[13];

  const size_t MB = 1024ull * 1024ull;
  char* ws = (char*)d_ws;
  unsigned short* buf0 = (unsigned short*)(ws);             // 64 MiB: h -> attno
  unsigned short* x2   = (unsigned short*)(ws + 64 * MB);   // 64 MiB: bf16 residual-1
  unsigned short* wqkv = (unsigned short*)(ws + 128 * MB);  // [768][256] bf16
  unsigned short* wmrg = wqkv + 768 * 256;                  // [256][256]
  unsigned short* w1t  = wmrg + 256 * 256;                  // [1024][256]
  unsigned short* w2t  = w1t + 1024 * 256;                  // [256][1024]
  float* relb          = (float*)(w2t + 256 * 1024);        // [8][64][64] f32
  unsigned short* xw   = (unsigned short*)(ws + 130 * MB);  // 64 MiB raw partitioned x
  unsigned short* Cbuf = (unsigned short*)(ws + 194 * MB);  // qkv chunk scratch

  size_t avail = ws_size > 194 * MB ? ws_size - 194 * MB : 0;
  int wc = 16;                                   // windows per qkv/attn chunk
  {
    const int cands[5] = {512, 256, 128, 64, 32};
    for (int i = 0; i < 5; i++)
      if ((size_t)cands[i] * 64 * 768 * 2 <= avail) { wc = cands[i]; break; }
  }

  cast_wt<256, 768><<<768, 256, 0, stream>>>(qkv_w, wqkv);
  cast_wt<256, 256><<<256, 256, 0, stream>>>(merge_w, wmrg);
  cast_wt<256, 1024><<<1024, 256, 0, stream>>>(mlp_w1, w1t);
  cast_wt<1024, 256><<<1024, 256, 0, stream>>>(mlp_w2, w2t);
  build_relb<<<128, 256, 0, stream>>>(bias_table, relb);

  part_ln1<<<1024, 256, 0, stream>>>(x, ln1_g, ln1_b, buf0, xw);

  for (int w0 = 0; w0 < 2048; w0 += wc) {
    gemm_qkv<<<dim3(wc * 64 / 128, 6), 256, 0, stream>>>(
        buf0 + (size_t)w0 * 64 * 256, wqkv, qkv_b, nullptr, Cbuf, 256, 768, 0);
    attn_k<<<dim3(wc, 8), 64, 0, stream>>>(Cbuf, relb, buf0 + (size_t)w0 * 64 * 256);
  }

  // merge projection + residual from xw (bf16 linear) -> x2 bf16
  gemm_merge<<<dim3(1024, 2), 256, 0, stream>>>(
      buf0, wmrg, merge_b, xw, x2, 256, 256, 0);

  // fused LN2 + MLP
  mlp_fused<<<2048, 256, 0, stream>>>(x2, w1t, mlp_b1, w2t, mlp_b2, ln2_g, ln2_b, (float*)d_out);
}

// Round 18
// 654.562 us; speedup vs baseline: 1.0307x; 1.0307x over previous
//
#include <hip/hip_runtime.h>

typedef __attribute__((ext_vector_type(8))) short short8;
typedef __attribute__((ext_vector_type(4))) short short4v;
typedef __attribute__((ext_vector_type(8))) unsigned short ushort8v;
typedef __attribute__((ext_vector_type(4))) float f32x4;
typedef __attribute__((ext_vector_type(4))) int int4v;
typedef __attribute__((ext_vector_type(4))) unsigned short ushort4v;
typedef __attribute__((ext_vector_type(2))) unsigned short ushort2v;

#define SCALE_F 0.0625f   // C^-0.5 = 256^-0.5
#define EPS_F 1e-5f

__device__ __forceinline__ float bf2f(unsigned short u) {
  unsigned int i = ((unsigned int)u) << 16;
  return __builtin_bit_cast(float, i);
}
__device__ __forceinline__ unsigned short f2bf(float f) {
  unsigned int i = __builtin_bit_cast(unsigned int, f);
  i += 0x7fffu + ((i >> 16) & 1u);
  return (unsigned short)(i >> 16);
}

// tanh-form GELU ~10 VALU ops; |err| < 5e-4 for |v|<2 (our sigma ~0.32).
__device__ __forceinline__ float fast_gelu(float v) {
  float s = v * v;
  float u = v * __builtin_fmaf(s, 0.0713548163f, 1.5957691216f);
  float e = __expf(u);
  float r = __builtin_amdgcn_rcpf(e + 1.f);
  return v - v * r;
}

__device__ __forceinline__ void gload_lds16(const unsigned short* g, unsigned short* l) {
  __builtin_amdgcn_global_load_lds(
      (const __attribute__((address_space(1))) void*)g,
      (__attribute__((address_space(3))) void*)l, 16, 0, 0);
}

// ---- cast weight [K,N] f32 -> [N,K] bf16 (transposed) ----
template<int K, int N>
__global__ void cast_wt(const float* __restrict__ src, unsigned short* __restrict__ dst) {
  int id = blockIdx.x * 256 + threadIdx.x;          // id = n*K + k
  if (id >= K * N) return;
  int k = id % K, n = id / K;
  dst[id] = f2bf(src[(size_t)k * N + n]);
}

// ---- precompute relative-position bias [head][i][j] ----
__global__ void build_relb(const float* __restrict__ table, float* __restrict__ relb) {
  int id = blockIdx.x * 256 + threadIdx.x;          // 8*64*64
  int h = id >> 12, i = (id >> 6) & 63, j = id & 63;
  int dy = (i >> 3) - (j >> 3) + 7;
  int dx = (i & 7) - (j & 7) + 7;
  relb[id] = table[(dy * 15 + dx) * 8 + h];
}

// ---- window partition + LN1 (coalesced transpose): x[B,C,64,64] ->
//      h bf16 [M,256] (normalized) AND xw bf16 [M,256] (raw, for merge residual)
#define PLN_RS 264   // LDS row stride in ushorts (256 + 8 pad)
__global__ __launch_bounds__(256) void part_ln1(
    const float* __restrict__ x, const float* __restrict__ g, const float* __restrict__ bb,
    unsigned short* __restrict__ h, unsigned short* __restrict__ xw) {
  __shared__ __align__(16) unsigned short t_lds[128 * PLN_RS];
  __shared__ float ps_sum[128][2];
  __shared__ float ps_ss[128][2];
  const int tid = threadIdx.x;
  const int bid = blockIdx.x;
  const int b = bid >> 5, wr = (bid >> 2) & 7, cp = bid & 3;
  const int r0 = wr * 8;            // image row base
  const int c0 = cp * 16;           // image col base

  // Phase 1: coalesced read + transpose to LDS [px][ch]
  const int q = tid & 3, r = (tid >> 2) & 7, cb = tid >> 5;   // cb in 0..7
  const float* xb = x + (size_t)b * 256 * 4096 + (size_t)(r0 + r) * 64 + c0 + q * 4;
#pragma unroll
  for (int it = 0; it < 16; it++) {
    int cpair = it * 8 + cb;                 // channel pair 0..127
    const float* p0 = xb + (size_t)(2 * cpair) * 4096;
    f32x4 v0 = *(const f32x4*)p0;
    f32x4 v1 = *(const f32x4*)(p0 + 4096);
#pragma unroll
    for (int j = 0; j < 4; j++) {
      int px = r * 16 + q * 4 + j;
      ushort2v u = { f2bf(v0[j]), f2bf(v1[j]) };
      *(ushort2v*)(&t_lds[px * PLN_RS + 2 * cpair]) = u;
    }
  }
  __syncthreads();

  // Phase 2: per-pixel stats (2 threads per pixel)
  {
    const int p = tid & 127, half = tid >> 7;
    float sum = 0.f, ss = 0.f;
#pragma unroll
    for (int i = 0; i < 16; i++) {
      ushort8v u = *(const ushort8v*)(&t_lds[p * PLN_RS + half * 128 + i * 8]);
#pragma unroll
      for (int e = 0; e < 8; e++) { float f = bf2f(u[e]); sum += f; ss += f * f; }
    }
    ps_sum[p][half] = sum;
    ps_ss[p][half] = ss;
  }
  __syncthreads();

  // Phase 3: normalize + coalesced write (h normalized, xw raw)
#pragma unroll
  for (int w = 0; w < 16; w++) {
    int id = w * 256 + tid;
    int p = id >> 5, ch = id & 31;
    float mu = (ps_sum[p][0] + ps_sum[p][1]) * (1.f / 256.f);
    float var = (ps_ss[p][0] + ps_ss[p][1]) * (1.f / 256.f) - mu * mu;
    float rs = rsqrtf(var + EPS_F);
    ushort8v u = *(const ushort8v*)(&t_lds[p * PLN_RS + ch * 8]);
    f32x4 g0 = *(const f32x4*)(g + ch * 8);
    f32x4 g1 = *(const f32x4*)(g + ch * 8 + 4);
    f32x4 b0 = *(const f32x4*)(bb + ch * 8);
    f32x4 b1 = *(const f32x4*)(bb + ch * 8 + 4);
    ushort8v o;
#pragma unroll
    for (int e = 0; e < 4; e++) {
      o[e]     = f2bf((bf2f(u[e])     - mu) * rs * g0[e] + b0[e]);
      o[e + 4] = f2bf((bf2f(u[e + 4]) - mu) * rs * g1[e] + b1[e]);
    }
    int rr = p >> 4, col = p & 15;
    size_t m = (size_t)b * 4096 + (size_t)(wr * 8 + cp * 2 + (col >> 3)) * 64 + rr * 8 + (col & 7);
    *(ushort8v*)(h + m * 256 + ch * 8) = o;
    *(ushort8v*)(xw + m * 256 + ch * 8) = u;   // raw x, window-partitioned
  }
}

// ---- GEMM: A bf16 [rows,K] x Bt bf16 [N,K] -> out, 128x128 tile, 4 waves ----
enum { EPI_QKV = 0, EPI_MERGE = 1 };

template<int EPI>
__device__ __forceinline__ void gemm_body(
    unsigned short* As, unsigned short* Bs,
    const unsigned short* __restrict__ A, const unsigned short* __restrict__ Bt,
    const float* __restrict__ bias, const void* __restrict__ res,
    void* __restrict__ out, int K, int N, long m_base) {
  const int tid = threadIdx.x;
  const int l15 = tid & 15, lhi = (tid & 63) >> 4;
  const int wid = tid >> 6, wm = wid >> 1, wn = wid & 1;
  const size_t m0 = (size_t)blockIdx.x * 128;
  const int n0 = blockIdx.y * 128;
  const int row_s = tid >> 3, kc8 = (tid & 7) * 8;   // staging coords

  auto stage = [&](int kb, int k0) {
#pragma unroll
    for (int i = 0; i < 4; i++) {
      int row = i * 32 + row_s;
      gload_lds16(A + (m0 + row) * (size_t)K + k0 + kc8, &As[kb * 8192 + (i * 256 + tid) * 8]);
      gload_lds16(Bt + (size_t)(n0 + row) * (size_t)K + k0 + kc8, &Bs[kb * 8192 + (i * 256 + tid) * 8]);
    }
  };

  f32x4 acc[4][4];
#pragma unroll
  for (int i = 0; i < 4; i++)
#pragma unroll
    for (int j = 0; j < 4; j++) acc[i][j] = (f32x4){0.f, 0.f, 0.f, 0.f};

  stage(0, 0);
  int kb = 0;
  for (int k0 = 0; k0 < K; k0 += 64, kb ^= 1) {
    if (k0 + 64 < K) {
      stage(kb ^ 1, k0 + 64);
      asm volatile("s_waitcnt vmcnt(8)" ::: "memory");
    } else {
      asm volatile("s_waitcnt vmcnt(0)" ::: "memory");
    }
    __builtin_amdgcn_s_barrier();
#pragma unroll
    for (int ks = 0; ks < 2; ks++) {
      short8 af[4], bfr[4];
#pragma unroll
      for (int t = 0; t < 4; t++) {
        af[t]  = *(const short8*)(&As[kb * 8192 + (wm * 64 + t * 16 + l15) * 64 + ks * 32 + lhi * 8]);
        bfr[t] = *(const short8*)(&Bs[kb * 8192 + (wn * 64 + t * 16 + l15) * 64 + ks * 32 + lhi * 8]);
      }
#pragma unroll
      for (int mt = 0; mt < 4; mt++)
#pragma unroll
        for (int nt = 0; nt < 4; nt++)
          acc[mt][nt] = __builtin_amdgcn_mfma_f32_16x16x32_bf16(af[mt], bfr[nt], acc[mt][nt], 0, 0, 0);
    }
    __builtin_amdgcn_s_barrier();
  }

#pragma unroll
  for (int mt = 0; mt < 4; mt++) {
#pragma unroll
    for (int nt = 0; nt < 4; nt++) {
      const size_t gml0 = m0 + wm * 64 + mt * 16 + lhi * 4;
      const size_t gm0 = gml0 + (size_t)m_base;
      const int gn = n0 + wn * 64 + nt * 16 + l15;
      if (EPI == EPI_QKV) {
#pragma unroll
        for (int r = 0; r < 4; r++)
          ((unsigned short*)out)[(gml0 + r) * (size_t)N + gn] = f2bf(acc[mt][nt][r] + bias[gn]);
      } else {  // EPI_MERGE: residual from pre-partitioned bf16 xw (linear, coalesced)
#pragma unroll
        for (int r = 0; r < 4; r++) {
          float v = acc[mt][nt][r] + bias[gn] +
                    bf2f(((const unsigned short*)res)[(gm0 + r) * 256 + gn]);
          ((unsigned short*)out)[(gm0 + r) * 256 + gn] = f2bf(v);
        }
      }
    }
  }
}

#define GEMM_WRAP(name, epi)                                                          \
__global__ __launch_bounds__(256) void name(                                          \
    const unsigned short* __restrict__ A, const unsigned short* __restrict__ Bt,      \
    const float* __restrict__ bias, const void* __restrict__ res,                     \
    void* __restrict__ out, int K, int N, long m_base) {                              \
  __shared__ __align__(16) unsigned short As[2 * 128 * 64];                           \
  __shared__ __align__(16) unsigned short Bs[2 * 128 * 64];                           \
  gemm_body<epi>(As, Bs, A, Bt, bias, res, out, K, N, m_base);                        \
}
GEMM_WRAP(gemm_qkv, EPI_QKV)
GEMM_WRAP(gemm_merge, EPI_MERGE)

// ---- fused LN2+MLP (R16 config: intra-loop ping-pong only, no cross-barrier
// carries — those spill (R17: +80MB scratch traffic). b1 loads hoisted above
// gemm1 (no barrier crossed, 2 VGPRs).
#define A2S 136   // 272B rows: 16B-aligned b128 reads
__global__ __launch_bounds__(256, 3) void mlp_fused(
    const unsigned short* __restrict__ x2, const unsigned short* __restrict__ w1t,
    const float* __restrict__ b1, const unsigned short* __restrict__ w2t,
    const float* __restrict__ b2, const float* __restrict__ ln2g,
    const float* __restrict__ ln2b, float* __restrict__ out) {
  __shared__ __align__(16) unsigned short Ash[64 * 256];
  __shared__ __align__(16) unsigned short A2sh[64 * A2S];
  const int tid = threadIdx.x;
  const int wid = tid >> 6, l = tid & 63, l15 = l & 15, lhi = l >> 4;
  const size_t m0 = (size_t)blockIdx.x * 64;

  // stage x2 rows into Ash LINEAR
#pragma unroll
  for (int i = 0; i < 8; i++) {
    int uidx = i * 256 + tid;                  // 16B unit 0..2047
    gload_lds16(x2 + m0 * 256 + uidx * 8, &Ash[uidx * 8]);
  }
  asm volatile("s_waitcnt vmcnt(0)" ::: "memory");
  __builtin_amdgcn_s_barrier();

  // LN2 in-place: ALL reads into regs BEFORE any write (wave-lockstep safe).
  {
    const int rl = l & 15;
    const int row = wid * 16 + rl;
    const int p = lhi;
    unsigned short* rp = &Ash[row * 256];
    short8 v[8];
#pragma unroll
    for (int e = 0; e < 8; e++) {
      int u = p * 8 + ((e + rl) & 7);          // rotated: unit%8 varies across rows
      v[e] = *(const short8*)(rp + u * 8);
    }
    float sum = 0.f, ss = 0.f;
#pragma unroll
    for (int e = 0; e < 8; e++)
#pragma unroll
      for (int j = 0; j < 8; j++) {
        float f = bf2f((unsigned short)v[e][j]);
        sum += f; ss += f * f;
      }
    sum += __shfl_xor(sum, 16, 64); ss += __shfl_xor(ss, 16, 64);
    sum += __shfl_xor(sum, 32, 64); ss += __shfl_xor(ss, 32, 64);
    float mu = sum * (1.f / 256.f);
    float var = ss * (1.f / 256.f) - mu * mu;
    float rs = rsqrtf(var + EPS_F);
    const int key = rl << 1;
#pragma unroll
    for (int e = 0; e < 8; e++) {
      int u = p * 8 + ((e + rl) & 7);
      f32x4 g0 = *(const f32x4*)(ln2g + u * 8);
      f32x4 g1 = *(const f32x4*)(ln2g + u * 8 + 4);
      f32x4 b0 = *(const f32x4*)(ln2b + u * 8);
      f32x4 b1v = *(const f32x4*)(ln2b + u * 8 + 4);
      ushort8v o;
#pragma unroll
      for (int j = 0; j < 4; j++) {
        o[j]     = f2bf((bf2f((unsigned short)v[e][j])     - mu) * rs * g0[j] + b0[j]);
        o[j + 4] = f2bf((bf2f((unsigned short)v[e][j + 4]) - mu) * rs * g1[j] + b1v[j]);
      }
      *(ushort8v*)(rp + (u ^ key) * 8) = o;
    }
  }
  __builtin_amdgcn_s_barrier();

  f32x4 oacc[4][4];
#pragma unroll
  for (int i = 0; i < 4; i++)
#pragma unroll
    for (int j = 0; j < 4; j++) oacc[i][j] = (f32x4){0.f, 0.f, 0.f, 0.f};

  for (int hs = 0; hs < 8; hs++) {
    const int hc0 = hs * 128 + wid * 32;
    // bias loads hoisted above gemm1: latency hides under the 8 MFMA iterations
    float bv0 = b1[hc0 + l15], bv1 = b1[hc0 + 16 + l15];

    f32x4 hacc[4][2];
#pragma unroll
    for (int i = 0; i < 4; i++) { hacc[i][0] = (f32x4){0.f,0.f,0.f,0.f}; hacc[i][1] = (f32x4){0.f,0.f,0.f,0.f}; }
    // GEMM1 with ping-pong prefetch of w1 fragments
    short8 bf1p[2][2];
#pragma unroll
    for (int nt = 0; nt < 2; nt++)
      bf1p[0][nt] = *(const short8*)(w1t + (size_t)(hc0 + nt * 16 + l15) * 256 + lhi * 8);
#pragma unroll
    for (int kst = 0; kst < 8; kst++) {
      if (kst < 7) {
#pragma unroll
        for (int nt = 0; nt < 2; nt++)
          bf1p[(kst + 1) & 1][nt] =
              *(const short8*)(w1t + (size_t)(hc0 + nt * 16 + l15) * 256 + (kst + 1) * 32 + lhi * 8);
      }
      short8 af[4];
#pragma unroll
      for (int mt = 0; mt < 4; mt++) {
        int su = (kst * 4 + lhi) ^ (l15 << 1);
        af[mt] = *(const short8*)(&Ash[(mt * 16 + l15) * 256 + su * 8]);
      }
#pragma unroll
      for (int mt = 0; mt < 4; mt++)
#pragma unroll
        for (int nt = 0; nt < 2; nt++)
          hacc[mt][nt] = __builtin_amdgcn_mfma_f32_16x16x32_bf16(af[mt], bf1p[kst & 1][nt], hacc[mt][nt], 0, 0, 0);
    }
    // bias + GELU -> A2sh
    {
#pragma unroll
      for (int mt = 0; mt < 4; mt++)
#pragma unroll
        for (int nt = 0; nt < 2; nt++) {
          float bv = nt ? bv1 : bv0;
          int kh = wid * 32 + nt * 16 + l15;
#pragma unroll
          for (int rr = 0; rr < 4; rr++) {
            float v = hacc[mt][nt][rr] + bv;
            A2sh[(mt * 16 + lhi * 4 + rr) * A2S + kh] = f2bf(fast_gelu(v));
          }
        }
    }
    __builtin_amdgcn_s_barrier();
    // GEMM2 with ping-pong prefetch of w2 fragments
    {
      const unsigned short* w2base = w2t + (size_t)(wid * 64 + l15) * 1024 + hs * 128 + lhi * 8;
      short8 bf2p[2][4];
#pragma unroll
      for (int nt = 0; nt < 4; nt++)
        bf2p[0][nt] = *(const short8*)(w2base + (size_t)(nt * 16) * 1024);
#pragma unroll
      for (int k2 = 0; k2 < 4; k2++) {
        if (k2 < 3) {
#pragma unroll
          for (int nt = 0; nt < 4; nt++)
            bf2p[(k2 + 1) & 1][nt] = *(const short8*)(w2base + (size_t)(nt * 16) * 1024 + (k2 + 1) * 32);
        }
        short8 a2[4];
#pragma unroll
        for (int mt = 0; mt < 4; mt++)
          a2[mt] = *(const short8*)(&A2sh[(mt * 16 + l15) * A2S + k2 * 32 + lhi * 8]);
        __builtin_amdgcn_s_setprio(1);
#pragma unroll
        for (int mt = 0; mt < 4; mt++)
#pragma unroll
          for (int nt = 0; nt < 4; nt++)
            oacc[mt][nt] = __builtin_amdgcn_mfma_f32_16x16x32_bf16(a2[mt], bf2p[k2 & 1][nt], oacc[mt][nt], 0, 0, 0);
        __builtin_amdgcn_s_setprio(0);
      }
    }
    __builtin_amdgcn_s_barrier();   // A2sh reuse next slice
  }

  // epilogue: + b2 + x2 residual, departition scatter (f32x4)
#pragma unroll
  for (int mt = 0; mt < 4; mt++) {
#pragma unroll
    for (int nt = 0; nt < 4; nt++) {
      size_t gm0 = m0 + mt * 16 + lhi * 4;
      int gn = wid * 64 + nt * 16 + l15;
      int bi = (int)(gm0 >> 12), gg = (int)((gm0 >> 6) & 63), s0 = (int)(gm0 & 63);
      size_t sp = (size_t)((gg >> 3) * 8 + (s0 >> 3)) * 64 + (gg & 7) * 8 + (s0 & 7);
      f32x4 o4;
#pragma unroll
      for (int r = 0; r < 4; r++)
        o4[r] = oacc[mt][nt][r] + b2[gn] + bf2f(x2[(gm0 + r) * 256 + gn]);
      *(f32x4*)(&out[((size_t)(bi * 256 + gn)) * 4096 + sp]) = o4;
    }
  }
}

// ---- attention: one wave per (window, head) ----
__global__ __launch_bounds__(64) void attn_k(
    const unsigned short* __restrict__ qkv, const float* __restrict__ relb,
    unsigned short* __restrict__ o) {
  __shared__ __align__(16) unsigned short p_lds[64 * 72];
  __shared__ __align__(16) unsigned short vt_lds[32 * 72];
  const int l = threadIdx.x;
  const int l15 = l & 15, lhi = l >> 4;
  const int w = blockIdx.x, head = blockIdx.y;
  const unsigned short* base = qkv + (size_t)w * 64 * 768 + head * 32;

  short8 aq[4], bk[4];
#pragma unroll
  for (int t = 0; t < 4; t++) {
    aq[t] = *(const short8*)(base + (t * 16 + l15) * 768 + lhi * 8);
    bk[t] = *(const short8*)(base + 256 + (t * 16 + l15) * 768 + lhi * 8);
  }
  f32x4 s[4][4];
#pragma unroll
  for (int i = 0; i < 4; i++)
#pragma unroll
    for (int j = 0; j < 4; j++) s[i][j] = (f32x4){0.f, 0.f, 0.f, 0.f};
#pragma unroll
  for (int mt = 0; mt < 4; mt++)
#pragma unroll
    for (int nt = 0; nt < 4; nt++)
      s[mt][nt] = __builtin_amdgcn_mfma_f32_16x16x32_bf16(aq[mt], bk[nt], s[mt][nt], 0, 0, 0);

  const float* rb = relb + head * 4096;
  float rsum[4][4];
#pragma unroll
  for (int mt = 0; mt < 4; mt++) {
#pragma unroll
    for (int r = 0; r < 4; r++) {
      int row = mt * 16 + lhi * 4 + r;
      float vv[4];
      float vmax = -1e30f;
#pragma unroll
      for (int nt = 0; nt < 4; nt++) {
        int col = nt * 16 + l15;
        float v = s[mt][nt][r] * SCALE_F + rb[row * 64 + col];
        vv[nt] = v;
        vmax = fmaxf(vmax, v);
      }
#pragma unroll
      for (int d = 1; d < 16; d <<= 1) vmax = fmaxf(vmax, __shfl_xor(vmax, d, 64));
      float sum = 0.f;
#pragma unroll
      for (int nt = 0; nt < 4; nt++) {
        float p = __expf(vv[nt] - vmax);
        sum += p;
        p_lds[row * 72 + nt * 16 + l15] = f2bf(p);
      }
#pragma unroll
      for (int d = 1; d < 16; d <<= 1) sum += __shfl_xor(sum, d, 64);
      rsum[mt][r] = 1.f / sum;
    }
  }

  // stage v^T: vt[dh][token]
#pragma unroll
  for (int j = 0; j < 4; j++) {
    short8 vv = *(const short8*)(base + 512 + l * 768 + j * 8);
#pragma unroll
    for (int e = 0; e < 8; e++)
      vt_lds[(j * 8 + e) * 72 + l] = (unsigned short)vv[e];
  }
  __syncthreads();

  f32x4 o2[4][2];
#pragma unroll
  for (int i = 0; i < 4; i++) { o2[i][0] = (f32x4){0.f,0.f,0.f,0.f}; o2[i][1] = (f32x4){0.f,0.f,0.f,0.f}; }
#pragma unroll
  for (int ks = 0; ks < 2; ks++) {
    short8 ap[4], bv[2];
#pragma unroll
    for (int t = 0; t < 4; t++)
      ap[t] = *(const short8*)(&p_lds[(t * 16 + l15) * 72 + ks * 32 + lhi * 8]);
#pragma unroll
    for (int t = 0; t < 2; t++)
      bv[t] = *(const short8*)(&vt_lds[(t * 16 + l15) * 72 + ks * 32 + lhi * 8]);
#pragma unroll
    for (int mt = 0; mt < 4; mt++)
#pragma unroll
      for (int n2 = 0; n2 < 2; n2++)
        o2[mt][n2] = __builtin_amdgcn_mfma_f32_16x16x32_bf16(ap[mt], bv[n2], o2[mt][n2], 0, 0, 0);
  }
#pragma unroll
  for (int mt = 0; mt < 4; mt++)
#pragma unroll
    for (int n2 = 0; n2 < 2; n2++)
#pragma unroll
      for (int r = 0; r < 4; r++) {
        int row = mt * 16 + lhi * 4 + r;
        int dh = n2 * 16 + l15;
        o[((size_t)w * 64 + row) * 256 + head * 32 + dh] = f2bf(o2[mt][n2][r] * rsum[mt][r]);
      }
}

extern "C" void kernel_launch(void* const* d_in, const int* in_sizes, int n_in,
                              void* d_out, int out_size, void* d_ws, size_t ws_size,
                              hipStream_t stream) {
  (void)in_sizes; (void)n_in; (void)out_size;
  const float* x          = (const float*)d_in[0];
  const float* ln1_g      = (const float*)d_in[1];
  const float* ln1_b      = (const float*)d_in[2];
  const float* qkv_w      = (const float*)d_in[3];
  const float* qkv_b      = (const float*)d_in[4];
  const float* merge_w    = (const float*)d_in[5];
  const float* merge_b    = (const float*)d_in[6];
  const float* bias_table = (const float*)d_in[7];
  const float* ln2_g      = (const float*)d_in[8];
  const float* ln2_b      = (const float*)d_in[9];
  const float* mlp_w1     = (const float*)d_in[10];
  const float* mlp_b1     = (const float*)d_in[11];
  const float* mlp_w2     = (const float*)d_in[12];
  const float* mlp_b2     = (const float*)d_in[13];

  const size_t MB = 1024ull * 1024ull;
  char* ws = (char*)d_ws;
  unsigned short* buf0 = (unsigned short*)(ws);             // 64 MiB: h -> attno
  unsigned short* x2   = (unsigned short*)(ws + 64 * MB);   // 64 MiB: bf16 residual-1
  unsigned short* wqkv = (unsigned short*)(ws + 128 * MB);  // [768][256] bf16
  unsigned short* wmrg = wqkv + 768 * 256;                  // [256][256]
  unsigned short* w1t  = wmrg + 256 * 256;                  // [1024][256]
  unsigned short* w2t  = w1t + 1024 * 256;                  // [256][1024]
  float* relb          = (float*)(w2t + 256 * 1024);        // [8][64][64] f32
  unsigned short* xw   = (unsigned short*)(ws + 130 * MB);  // 64 MiB raw partitioned x
  unsigned short* Cbuf = (unsigned short*)(ws + 194 * MB);  // qkv chunk scratch

  size_t avail = ws_size > 194 * MB ? ws_size - 194 * MB : 0;
  int wc = 16;                                   // windows per qkv/attn chunk
  {
    const int cands[5] = {512, 256, 128, 64, 32};
    for (int i = 0; i < 5; i++)
      if ((size_t)cands[i] * 64 * 768 * 2 <= avail) { wc = cands[i]; break; }
  }

  cast_wt<256, 768><<<768, 256, 0, stream>>>(qkv_w, wqkv);
  cast_wt<256, 256><<<256, 256, 0, stream>>>(merge_w, wmrg);
  cast_wt<256, 1024><<<1024, 256, 0, stream>>>(mlp_w1, w1t);
  cast_wt<1024, 256><<<1024, 256, 0, stream>>>(mlp_w2, w2t);
  build_relb<<<128, 256, 0, stream>>>(bias_table, relb);

  part_ln1<<<1024, 256, 0, stream>>>(x, ln1_g, ln1_b, buf0, xw);

  for (int w0 = 0; w0 < 2048; w0 += wc) {
    gemm_qkv<<<dim3(wc * 64 / 128, 6), 256, 0, stream>>>(
        buf0 + (size_t)w0 * 64 * 256, wqkv, qkv_b, nullptr, Cbuf, 256, 768, 0);
    attn_k<<<dim3(wc, 8), 64, 0, stream>>>(Cbuf, relb, buf0 + (size_t)w0 * 64 * 256);
  }

  // merge projection + residual from xw (bf16 linear) -> x2 bf16
  gemm_merge<<<dim3(1024, 2), 256, 0, stream>>>(
      buf0, wmrg, merge_b, xw, x2, 256, 256, 0);

  // fused LN2 + MLP
  mlp_fused<<<2048, 256, 0, stream>>>(x2, w1t, mlp_b1, w2t, mlp_b2, ln2_g, ln2_b, (float*)d_out);
}

// Round 19
// 650.425 us; speedup vs baseline: 1.0372x; 1.0064x over previous
//
#include <hip/hip_runtime.h>

typedef __attribute__((ext_vector_type(8))) short short8;
typedef __attribute__((ext_vector_type(4))) short short4v;
typedef __attribute__((ext_vector_type(8))) unsigned short ushort8v;
typedef __attribute__((ext_vector_type(4))) float f32x4;
typedef __attribute__((ext_vector_type(4))) int int4v;
typedef __attribute__((ext_vector_type(4))) unsigned short ushort4v;
typedef __attribute__((ext_vector_type(2))) unsigned short ushort2v;

#define SCALE_F 0.0625f   // C^-0.5 = 256^-0.5
#define EPS_F 1e-5f

__device__ __forceinline__ float bf2f(unsigned short u) {
  unsigned int i = ((unsigned int)u) << 16;
  return __builtin_bit_cast(float, i);
}
__device__ __forceinline__ unsigned short f2bf(float f) {
  unsigned int i = __builtin_bit_cast(unsigned int, f);
  i += 0x7fffu + ((i >> 16) & 1u);
  return (unsigned short)(i >> 16);
}

// tanh-form GELU ~10 VALU ops; |err| < 5e-4 for |v|<2 (our sigma ~0.32).
__device__ __forceinline__ float fast_gelu(float v) {
  float s = v * v;
  float u = v * __builtin_fmaf(s, 0.0713548163f, 1.5957691216f);
  float e = __expf(u);
  float r = __builtin_amdgcn_rcpf(e + 1.f);
  return v - v * r;
}

__device__ __forceinline__ void gload_lds16(const unsigned short* g, unsigned short* l) {
  __builtin_amdgcn_global_load_lds(
      (const __attribute__((address_space(1))) void*)g,
      (__attribute__((address_space(3))) void*)l, 16, 0, 0);
}

// ---- cast weight [K,N] f32 -> [N,K] bf16 (transposed) ----
template<int K, int N>
__global__ void cast_wt(const float* __restrict__ src, unsigned short* __restrict__ dst) {
  int id = blockIdx.x * 256 + threadIdx.x;          // id = n*K + k
  if (id >= K * N) return;
  int k = id % K, n = id / K;
  dst[id] = f2bf(src[(size_t)k * N + n]);
}

// ---- precompute relative-position bias [head][i][j] ----
__global__ void build_relb(const float* __restrict__ table, float* __restrict__ relb) {
  int id = blockIdx.x * 256 + threadIdx.x;          // 8*64*64
  int h = id >> 12, i = (id >> 6) & 63, j = id & 63;
  int dy = (i >> 3) - (j >> 3) + 7;
  int dx = (i & 7) - (j & 7) + 7;
  relb[id] = table[(dy * 15 + dx) * 8 + h];
}

// ---- window partition + LN1 (coalesced transpose): x[B,C,64,64] ->
//      h bf16 [M,256] (normalized) AND xw bf16 [M,256] (raw, for merge residual)
#define PLN_RS 264   // LDS row stride in ushorts (256 + 8 pad)
__global__ __launch_bounds__(256) void part_ln1(
    const float* __restrict__ x, const float* __restrict__ g, const float* __restrict__ bb,
    unsigned short* __restrict__ h, unsigned short* __restrict__ xw) {
  __shared__ __align__(16) unsigned short t_lds[128 * PLN_RS];
  __shared__ float ps_sum[128][2];
  __shared__ float ps_ss[128][2];
  const int tid = threadIdx.x;
  const int bid = blockIdx.x;
  const int b = bid >> 5, wr = (bid >> 2) & 7, cp = bid & 3;
  const int r0 = wr * 8;            // image row base
  const int c0 = cp * 16;           // image col base

  // Phase 1: coalesced read + transpose to LDS [px][ch]
  const int q = tid & 3, r = (tid >> 2) & 7, cb = tid >> 5;   // cb in 0..7
  const float* xb = x + (size_t)b * 256 * 4096 + (size_t)(r0 + r) * 64 + c0 + q * 4;
#pragma unroll
  for (int it = 0; it < 16; it++) {
    int cpair = it * 8 + cb;                 // channel pair 0..127
    const float* p0 = xb + (size_t)(2 * cpair) * 4096;
    f32x4 v0 = *(const f32x4*)p0;
    f32x4 v1 = *(const f32x4*)(p0 + 4096);
#pragma unroll
    for (int j = 0; j < 4; j++) {
      int px = r * 16 + q * 4 + j;
      ushort2v u = { f2bf(v0[j]), f2bf(v1[j]) };
      *(ushort2v*)(&t_lds[px * PLN_RS + 2 * cpair]) = u;
    }
  }
  __syncthreads();

  // Phase 2: per-pixel stats (2 threads per pixel)
  {
    const int p = tid & 127, half = tid >> 7;
    float sum = 0.f, ss = 0.f;
#pragma unroll
    for (int i = 0; i < 16; i++) {
      ushort8v u = *(const ushort8v*)(&t_lds[p * PLN_RS + half * 128 + i * 8]);
#pragma unroll
      for (int e = 0; e < 8; e++) { float f = bf2f(u[e]); sum += f; ss += f * f; }
    }
    ps_sum[p][half] = sum;
    ps_ss[p][half] = ss;
  }
  __syncthreads();

  // Phase 3: normalize + coalesced write (h normalized, xw raw)
#pragma unroll
  for (int w = 0; w < 16; w++) {
    int id = w * 256 + tid;
    int p = id >> 5, ch = id & 31;
    float mu = (ps_sum[p][0] + ps_sum[p][1]) * (1.f / 256.f);
    float var = (ps_ss[p][0] + ps_ss[p][1]) * (1.f / 256.f) - mu * mu;
    float rs = rsqrtf(var + EPS_F);
    ushort8v u = *(const ushort8v*)(&t_lds[p * PLN_RS + ch * 8]);
    f32x4 g0 = *(const f32x4*)(g + ch * 8);
    f32x4 g1 = *(const f32x4*)(g + ch * 8 + 4);
    f32x4 b0 = *(const f32x4*)(bb + ch * 8);
    f32x4 b1 = *(const f32x4*)(bb + ch * 8 + 4);
    ushort8v o;
#pragma unroll
    for (int e = 0; e < 4; e++) {
      o[e]     = f2bf((bf2f(u[e])     - mu) * rs * g0[e] + b0[e]);
      o[e + 4] = f2bf((bf2f(u[e + 4]) - mu) * rs * g1[e] + b1[e]);
    }
    int rr = p >> 4, col = p & 15;
    size_t m = (size_t)b * 4096 + (size_t)(wr * 8 + cp * 2 + (col >> 3)) * 64 + rr * 8 + (col & 7);
    *(ushort8v*)(h + m * 256 + ch * 8) = o;
    *(ushort8v*)(xw + m * 256 + ch * 8) = u;   // raw x, window-partitioned
  }
}

// ---- GEMM: A bf16 [rows,K] x Bt bf16 [N,K] -> out, 128x128 tile, 4 waves ----
enum { EPI_QKV = 0, EPI_MERGE = 1 };

template<int EPI>
__device__ __forceinline__ void gemm_body(
    unsigned short* As, unsigned short* Bs,
    const unsigned short* __restrict__ A, const unsigned short* __restrict__ Bt,
    const float* __restrict__ bias, const void* __restrict__ res,
    void* __restrict__ out, int K, int N, long m_base) {
  const int tid = threadIdx.x;
  const int l15 = tid & 15, lhi = (tid & 63) >> 4;
  const int wid = tid >> 6, wm = wid >> 1, wn = wid & 1;
  const size_t m0 = (size_t)blockIdx.x * 128;
  const int n0 = blockIdx.y * 128;
  const int row_s = tid >> 3, kc8 = (tid & 7) * 8;   // staging coords

  auto stage = [&](int kb, int k0) {
#pragma unroll
    for (int i = 0; i < 4; i++) {
      int row = i * 32 + row_s;
      gload_lds16(A + (m0 + row) * (size_t)K + k0 + kc8, &As[kb * 8192 + (i * 256 + tid) * 8]);
      gload_lds16(Bt + (size_t)(n0 + row) * (size_t)K + k0 + kc8, &Bs[kb * 8192 + (i * 256 + tid) * 8]);
    }
  };

  f32x4 acc[4][4];
#pragma unroll
  for (int i = 0; i < 4; i++)
#pragma unroll
    for (int j = 0; j < 4; j++) acc[i][j] = (f32x4){0.f, 0.f, 0.f, 0.f};

  stage(0, 0);
  int kb = 0;
  for (int k0 = 0; k0 < K; k0 += 64, kb ^= 1) {
    if (k0 + 64 < K) {
      stage(kb ^ 1, k0 + 64);
      asm volatile("s_waitcnt vmcnt(8)" ::: "memory");
    } else {
      asm volatile("s_waitcnt vmcnt(0)" ::: "memory");
    }
    __builtin_amdgcn_s_barrier();
#pragma unroll
    for (int ks = 0; ks < 2; ks++) {
      short8 af[4], bfr[4];
#pragma unroll
      for (int t = 0; t < 4; t++) {
        af[t]  = *(const short8*)(&As[kb * 8192 + (wm * 64 + t * 16 + l15) * 64 + ks * 32 + lhi * 8]);
        bfr[t] = *(const short8*)(&Bs[kb * 8192 + (wn * 64 + t * 16 + l15) * 64 + ks * 32 + lhi * 8]);
      }
#pragma unroll
      for (int mt = 0; mt < 4; mt++)
#pragma unroll
        for (int nt = 0; nt < 4; nt++)
          acc[mt][nt] = __builtin_amdgcn_mfma_f32_16x16x32_bf16(af[mt], bfr[nt], acc[mt][nt], 0, 0, 0);
    }
    __builtin_amdgcn_s_barrier();
  }

#pragma unroll
  for (int mt = 0; mt < 4; mt++) {
#pragma unroll
    for (int nt = 0; nt < 4; nt++) {
      const size_t gml0 = m0 + wm * 64 + mt * 16 + lhi * 4;
      const size_t gm0 = gml0 + (size_t)m_base;
      const int gn = n0 + wn * 64 + nt * 16 + l15;
      if (EPI == EPI_QKV) {
#pragma unroll
        for (int r = 0; r < 4; r++)
          ((unsigned short*)out)[(gml0 + r) * (size_t)N + gn] = f2bf(acc[mt][nt][r] + bias[gn]);
      } else {  // EPI_MERGE: residual from pre-partitioned bf16 xw (linear, coalesced)
#pragma unroll
        for (int r = 0; r < 4; r++) {
          float v = acc[mt][nt][r] + bias[gn] +
                    bf2f(((const unsigned short*)res)[(gm0 + r) * 256 + gn]);
          ((unsigned short*)out)[(gm0 + r) * 256 + gn] = f2bf(v);
        }
      }
    }
  }
}

#define GEMM_WRAP(name, epi)                                                          \
__global__ __launch_bounds__(256) void name(                                          \
    const unsigned short* __restrict__ A, const unsigned short* __restrict__ Bt,      \
    const float* __restrict__ bias, const void* __restrict__ res,                     \
    void* __restrict__ out, int K, int N, long m_base) {                              \
  __shared__ __align__(16) unsigned short As[2 * 128 * 64];                           \
  __shared__ __align__(16) unsigned short Bs[2 * 128 * 64];                           \
  gemm_body<epi>(As, Bs, A, Bt, bias, res, out, K, N, m_base);                        \
}
GEMM_WRAP(gemm_qkv, EPI_QKV)
GEMM_WRAP(gemm_merge, EPI_MERGE)

// ---- fused LN2+MLP (R18 config, frozen) ----
#define A2S 136   // 272B rows: 16B-aligned b128 reads
__global__ __launch_bounds__(256, 3) void mlp_fused(
    const unsigned short* __restrict__ x2, const unsigned short* __restrict__ w1t,
    const float* __restrict__ b1, const unsigned short* __restrict__ w2t,
    const float* __restrict__ b2, const float* __restrict__ ln2g,
    const float* __restrict__ ln2b, float* __restrict__ out) {
  __shared__ __align__(16) unsigned short Ash[64 * 256];
  __shared__ __align__(16) unsigned short A2sh[64 * A2S];
  const int tid = threadIdx.x;
  const int wid = tid >> 6, l = tid & 63, l15 = l & 15, lhi = l >> 4;
  const size_t m0 = (size_t)blockIdx.x * 64;

  // stage x2 rows into Ash LINEAR
#pragma unroll
  for (int i = 0; i < 8; i++) {
    int uidx = i * 256 + tid;                  // 16B unit 0..2047
    gload_lds16(x2 + m0 * 256 + uidx * 8, &Ash[uidx * 8]);
  }
  asm volatile("s_waitcnt vmcnt(0)" ::: "memory");
  __builtin_amdgcn_s_barrier();

  // LN2 in-place: ALL reads into regs BEFORE any write (wave-lockstep safe).
  {
    const int rl = l & 15;
    const int row = wid * 16 + rl;
    const int p = lhi;
    unsigned short* rp = &Ash[row * 256];
    short8 v[8];
#pragma unroll
    for (int e = 0; e < 8; e++) {
      int u = p * 8 + ((e + rl) & 7);          // rotated: unit%8 varies across rows
      v[e] = *(const short8*)(rp + u * 8);
    }
    float sum = 0.f, ss = 0.f;
#pragma unroll
    for (int e = 0; e < 8; e++)
#pragma unroll
      for (int j = 0; j < 8; j++) {
        float f = bf2f((unsigned short)v[e][j]);
        sum += f; ss += f * f;
      }
    sum += __shfl_xor(sum, 16, 64); ss += __shfl_xor(ss, 16, 64);
    sum += __shfl_xor(sum, 32, 64); ss += __shfl_xor(ss, 32, 64);
    float mu = sum * (1.f / 256.f);
    float var = ss * (1.f / 256.f) - mu * mu;
    float rs = rsqrtf(var + EPS_F);
    const int key = rl << 1;
#pragma unroll
    for (int e = 0; e < 8; e++) {
      int u = p * 8 + ((e + rl) & 7);
      f32x4 g0 = *(const f32x4*)(ln2g + u * 8);
      f32x4 g1 = *(const f32x4*)(ln2g + u * 8 + 4);
      f32x4 b0 = *(const f32x4*)(ln2b + u * 8);
      f32x4 b1v = *(const f32x4*)(ln2b + u * 8 + 4);
      ushort8v o;
#pragma unroll
      for (int j = 0; j < 4; j++) {
        o[j]     = f2bf((bf2f((unsigned short)v[e][j])     - mu) * rs * g0[j] + b0[j]);
        o[j + 4] = f2bf((bf2f((unsigned short)v[e][j + 4]) - mu) * rs * g1[j] + b1v[j]);
      }
      *(ushort8v*)(rp + (u ^ key) * 8) = o;
    }
  }
  __builtin_amdgcn_s_barrier();

  f32x4 oacc[4][4];
#pragma unroll
  for (int i = 0; i < 4; i++)
#pragma unroll
    for (int j = 0; j < 4; j++) oacc[i][j] = (f32x4){0.f, 0.f, 0.f, 0.f};

  for (int hs = 0; hs < 8; hs++) {
    const int hc0 = hs * 128 + wid * 32;
    // bias loads hoisted above gemm1: latency hides under the 8 MFMA iterations
    float bv0 = b1[hc0 + l15], bv1 = b1[hc0 + 16 + l15];

    f32x4 hacc[4][2];
#pragma unroll
    for (int i = 0; i < 4; i++) { hacc[i][0] = (f32x4){0.f,0.f,0.f,0.f}; hacc[i][1] = (f32x4){0.f,0.f,0.f,0.f}; }
    // GEMM1 with ping-pong prefetch of w1 fragments
    short8 bf1p[2][2];
#pragma unroll
    for (int nt = 0; nt < 2; nt++)
      bf1p[0][nt] = *(const short8*)(w1t + (size_t)(hc0 + nt * 16 + l15) * 256 + lhi * 8);
#pragma unroll
    for (int kst = 0; kst < 8; kst++) {
      if (kst < 7) {
#pragma unroll
        for (int nt = 0; nt < 2; nt++)
          bf1p[(kst + 1) & 1][nt] =
              *(const short8*)(w1t + (size_t)(hc0 + nt * 16 + l15) * 256 + (kst + 1) * 32 + lhi * 8);
      }
      short8 af[4];
#pragma unroll
      for (int mt = 0; mt < 4; mt++) {
        int su = (kst * 4 + lhi) ^ (l15 << 1);
        af[mt] = *(const short8*)(&Ash[(mt * 16 + l15) * 256 + su * 8]);
      }
#pragma unroll
      for (int mt = 0; mt < 4; mt++)
#pragma unroll
        for (int nt = 0; nt < 2; nt++)
          hacc[mt][nt] = __builtin_amdgcn_mfma_f32_16x16x32_bf16(af[mt], bf1p[kst & 1][nt], hacc[mt][nt], 0, 0, 0);
    }
    // bias + GELU -> A2sh
    {
#pragma unroll
      for (int mt = 0; mt < 4; mt++)
#pragma unroll
        for (int nt = 0; nt < 2; nt++) {
          float bv = nt ? bv1 : bv0;
          int kh = wid * 32 + nt * 16 + l15;
#pragma unroll
          for (int rr = 0; rr < 4; rr++) {
            float v = hacc[mt][nt][rr] + bv;
            A2sh[(mt * 16 + lhi * 4 + rr) * A2S + kh] = f2bf(fast_gelu(v));
          }
        }
    }
    __builtin_amdgcn_s_barrier();
    // GEMM2 with ping-pong prefetch of w2 fragments
    {
      const unsigned short* w2base = w2t + (size_t)(wid * 64 + l15) * 1024 + hs * 128 + lhi * 8;
      short8 bf2p[2][4];
#pragma unroll
      for (int nt = 0; nt < 4; nt++)
        bf2p[0][nt] = *(const short8*)(w2base + (size_t)(nt * 16) * 1024);
#pragma unroll
      for (int k2 = 0; k2 < 4; k2++) {
        if (k2 < 3) {
#pragma unroll
          for (int nt = 0; nt < 4; nt++)
            bf2p[(k2 + 1) & 1][nt] = *(const short8*)(w2base + (size_t)(nt * 16) * 1024 + (k2 + 1) * 32);
        }
        short8 a2[4];
#pragma unroll
        for (int mt = 0; mt < 4; mt++)
          a2[mt] = *(const short8*)(&A2sh[(mt * 16 + l15) * A2S + k2 * 32 + lhi * 8]);
        __builtin_amdgcn_s_setprio(1);
#pragma unroll
        for (int mt = 0; mt < 4; mt++)
#pragma unroll
          for (int nt = 0; nt < 4; nt++)
            oacc[mt][nt] = __builtin_amdgcn_mfma_f32_16x16x32_bf16(a2[mt], bf2p[k2 & 1][nt], oacc[mt][nt], 0, 0, 0);
        __builtin_amdgcn_s_setprio(0);
      }
    }
    __builtin_amdgcn_s_barrier();   // A2sh reuse next slice
  }

  // epilogue: + b2 + x2 residual, departition scatter (f32x4)
#pragma unroll
  for (int mt = 0; mt < 4; mt++) {
#pragma unroll
    for (int nt = 0; nt < 4; nt++) {
      size_t gm0 = m0 + mt * 16 + lhi * 4;
      int gn = wid * 64 + nt * 16 + l15;
      int bi = (int)(gm0 >> 12), gg = (int)((gm0 >> 6) & 63), s0 = (int)(gm0 & 63);
      size_t sp = (size_t)((gg >> 3) * 8 + (s0 >> 3)) * 64 + (gg & 7) * 8 + (s0 & 7);
      f32x4 o4;
#pragma unroll
      for (int r = 0; r < 4; r++)
        o4[r] = oacc[mt][nt][r] + b2[gn] + bf2f(x2[(gm0 + r) * 256 + gn]);
      *(f32x4*)(&out[((size_t)(bi * 256 + gn)) * 4096 + sp]) = o4;
    }
  }
}

// ---- attention: one wave per (window, head); V loads hoisted above QK^T ----
__global__ __launch_bounds__(64) void attn_k(
    const unsigned short* __restrict__ qkv, const float* __restrict__ relb,
    unsigned short* __restrict__ o) {
  __shared__ __align__(16) unsigned short p_lds[64 * 72];
  __shared__ __align__(16) unsigned short vt_lds[32 * 72];
  const int l = threadIdx.x;
  const int l15 = l & 15, lhi = l >> 4;
  const int w = blockIdx.x, head = blockIdx.y;
  const unsigned short* base = qkv + (size_t)w * 64 * 768 + head * 32;

  short8 aq[4], bk[4], vv[4];
#pragma unroll
  for (int t = 0; t < 4; t++) {
    aq[t] = *(const short8*)(base + (t * 16 + l15) * 768 + lhi * 8);
    bk[t] = *(const short8*)(base + 256 + (t * 16 + l15) * 768 + lhi * 8);
  }
  // V loads issued early: ~500cy latency hides under QK^T MFMAs + softmax
#pragma unroll
  for (int j = 0; j < 4; j++)
    vv[j] = *(const short8*)(base + 512 + l * 768 + j * 8);

  f32x4 s[4][4];
#pragma unroll
  for (int i = 0; i < 4; i++)
#pragma unroll
    for (int j = 0; j < 4; j++) s[i][j] = (f32x4){0.f, 0.f, 0.f, 0.f};
#pragma unroll
  for (int mt = 0; mt < 4; mt++)
#pragma unroll
    for (int nt = 0; nt < 4; nt++)
      s[mt][nt] = __builtin_amdgcn_mfma_f32_16x16x32_bf16(aq[mt], bk[nt], s[mt][nt], 0, 0, 0);

  const float* rb = relb + head * 4096;
  float rsum[4][4];
#pragma unroll
  for (int mt = 0; mt < 4; mt++) {
#pragma unroll
    for (int r = 0; r < 4; r++) {
      int row = mt * 16 + lhi * 4 + r;
      float vvx[4];
      float vmax = -1e30f;
#pragma unroll
      for (int nt = 0; nt < 4; nt++) {
        int col = nt * 16 + l15;
        float v = s[mt][nt][r] * SCALE_F + rb[row * 64 + col];
        vvx[nt] = v;
        vmax = fmaxf(vmax, v);
      }
#pragma unroll
      for (int d = 1; d < 16; d <<= 1) vmax = fmaxf(vmax, __shfl_xor(vmax, d, 64));
      float sum = 0.f;
#pragma unroll
      for (int nt = 0; nt < 4; nt++) {
        float p = __expf(vvx[nt] - vmax);
        sum += p;
        p_lds[row * 72 + nt * 16 + l15] = f2bf(p);
      }
#pragma unroll
      for (int d = 1; d < 16; d <<= 1) sum += __shfl_xor(sum, d, 64);
      rsum[mt][r] = 1.f / sum;
    }
  }

  // stage v^T: vt[dh][token] (loads already in vv)
#pragma unroll
  for (int j = 0; j < 4; j++) {
#pragma unroll
    for (int e = 0; e < 8; e++)
      vt_lds[(j * 8 + e) * 72 + l] = (unsigned short)vv[j][e];
  }
  __syncthreads();

  f32x4 o2[4][2];
#pragma unroll
  for (int i = 0; i < 4; i++) { o2[i][0] = (f32x4){0.f,0.f,0.f,0.f}; o2[i][1] = (f32x4){0.f,0.f,0.f,0.f}; }
#pragma unroll
  for (int ks = 0; ks < 2; ks++) {
    short8 ap[4], bv[2];
#pragma unroll
    for (int t = 0; t < 4; t++)
      ap[t] = *(const short8*)(&p_lds[(t * 16 + l15) * 72 + ks * 32 + lhi * 8]);
#pragma unroll
    for (int t = 0; t < 2; t++)
      bv[t] = *(const short8*)(&vt_lds[(t * 16 + l15) * 72 + ks * 32 + lhi * 8]);
#pragma unroll
    for (int mt = 0; mt < 4; mt++)
#pragma unroll
      for (int n2 = 0; n2 < 2; n2++)
        o2[mt][n2] = __builtin_amdgcn_mfma_f32_16x16x32_bf16(ap[mt], bv[n2], o2[mt][n2], 0, 0, 0);
  }
#pragma unroll
  for (int mt = 0; mt < 4; mt++)
#pragma unroll
    for (int n2 = 0; n2 < 2; n2++)
#pragma unroll
      for (int r = 0; r < 4; r++) {
        int row = mt * 16 + lhi * 4 + r;
        int dh = n2 * 16 + l15;
        o[((size_t)w * 64 + row) * 256 + head * 32 + dh] = f2bf(o2[mt][n2][r] * rsum[mt][r]);
      }
}

extern "C" void kernel_launch(void* const* d_in, const int* in_sizes, int n_in,
                              void* d_out, int out_size, void* d_ws, size_t ws_size,
                              hipStream_t stream) {
  (void)in_sizes; (void)n_in; (void)out_size;
  const float* x          = (const float*)d_in[0];
  const float* ln1_g      = (const float*)d_in[1];
  const float* ln1_b      = (const float*)d_in[2];
  const float* qkv_w      = (const float*)d_in[3];
  const float* qkv_b      = (const float*)d_in[4];
  const float* merge_w    = (const float*)d_in[5];
  const float* merge_b    = (const float*)d_in[6];
  const float* bias_table = (const float*)d_in[7];
  const float* ln2_g      = (const float*)d_in[8];
  const float* ln2_b      = (const float*)d_in[9];
  const float* mlp_w1     = (const float*)d_in[10];
  const float* mlp_b1     = (const float*)d_in[11];
  const float* mlp_w2     = (const float*)d_in[12];
  const float* mlp_b2     = (const float*)d_in[13];

  const size_t MB = 1024ull * 1024ull;
  char* ws = (char*)d_ws;
  unsigned short* buf0 = (unsigned short*)(ws);             // 64 MiB: h -> attno
  unsigned short* x2   = (unsigned short*)(ws + 64 * MB);   // 64 MiB: bf16 residual-1
  unsigned short* wqkv = (unsigned short*)(ws + 128 * MB);  // [768][256] bf16
  unsigned short* wmrg = wqkv + 768 * 256;                  // [256][256]
  unsigned short* w1t  = wmrg + 256 * 256;                  // [1024][256]
  unsigned short* w2t  = w1t + 1024 * 256;                  // [256][1024]
  float* relb          = (float*)(w2t + 256 * 1024);        // [8][64][64] f32
  unsigned short* xw   = (unsigned short*)(ws + 130 * MB);  // 64 MiB raw partitioned x
  unsigned short* Cbuf = (unsigned short*)(ws + 194 * MB);  // qkv chunk scratch

  size_t avail = ws_size > 194 * MB ? ws_size - 194 * MB : 0;
  int wc = 16;                                   // windows per qkv/attn chunk
  {
    const int cands[6] = {1024, 512, 256, 128, 64, 32};
    for (int i = 0; i < 6; i++)
      if ((size_t)cands[i] * 64 * 768 * 2 <= avail) { wc = cands[i]; break; }
  }

  cast_wt<256, 768><<<768, 256, 0, stream>>>(qkv_w, wqkv);
  cast_wt<256, 256><<<256, 256, 0, stream>>>(merge_w, wmrg);
  cast_wt<256, 1024><<<1024, 256, 0, stream>>>(mlp_w1, w1t);
  cast_wt<1024, 256><<<1024, 256, 0, stream>>>(mlp_w2, w2t);
  build_relb<<<128, 256, 0, stream>>>(bias_table, relb);

  part_ln1<<<1024, 256, 0, stream>>>(x, ln1_g, ln1_b, buf0, xw);

  for (int w0 = 0; w0 < 2048; w0 += wc) {
    gemm_qkv<<<dim3(wc * 64 / 128, 6), 256, 0, stream>>>(
        buf0 + (size_t)w0 * 64 * 256, wqkv, qkv_b, nullptr, Cbuf, 256, 768, 0);
    attn_k<<<dim3(wc, 8), 64, 0, stream>>>(Cbuf, relb, buf0 + (size_t)w0 * 64 * 256);
  }

  // merge projection + residual from xw (bf16 linear) -> x2 bf16
  gemm_merge<<<dim3(1024, 2), 256, 0, stream>>>(
      buf0, wmrg, merge_b, xw, x2, 256, 256, 0);

  // fused LN2 + MLP
  mlp_fused<<<2048, 256, 0, stream>>>(x2, w1t, mlp_b1, w2t, mlp_b2, ln2_g, ln2_b, (float*)d_out);
}